// Round 1
// baseline (75.304 us; speedup 1.0000x reference)
//
#include <hip/hip_runtime.h>

// Block = 256 threads = 32 points x 8 tensors.
// Stage the block's Lgen slab (256*9 floats = 9216 B) and C slab
// (32*9 floats = 1152 B) into LDS with fully-coalesced float4 copies,
// then each thread reads its 9 floats from LDS (stride-9 words ->
// coprime with 32 banks -> conflict-free; l/l+32 2-way alias is free).
// This replaces 18 scattered dword loads/thread (~36 cache lines per
// instruction) with ~2.5 fully-coalesced float4 loads/thread.

constexpr int TPB = 256;

__global__ __launch_bounds__(TPB) void gik_kernel(
    const float* __restrict__ Lg,
    const float* __restrict__ C,
    float* __restrict__ out,
    int total)  // N*8
{
    __shared__ float lgs[TPB * 9];        // 9216 B
    __shared__ float cs[(TPB / 8) * 9];   // 1152 B

    const int tid  = threadIdx.x;
    const int base = blockIdx.x * TPB;    // first (n,k) pair of this block

    float c00, c01, c02, c10, c11, c12, c20, c21, c22;
    float l0, l1, l2, l3, l4, l5, l6, l7, l8;

    const bool full = (base + TPB <= total);
    if (full) {
        // ---- coalesced staging: Lgen slab = 576 float4, C slab = 72 float4 ----
        const float4* gl4 = reinterpret_cast<const float4*>(Lg + (size_t)base * 9);
        float4* sl4 = reinterpret_cast<float4*>(lgs);
        float4 a0 = gl4[tid];
        float4 a1 = gl4[tid + TPB];
        float4 a2;
        if (tid < 64) a2 = gl4[tid + 2 * TPB];
        float4 ac;
        const float4* gc4 = reinterpret_cast<const float4*>(C + (size_t)(base >> 3) * 9);
        if (tid < 72) ac = gc4[tid];

        sl4[tid]       = a0;
        sl4[tid + TPB] = a1;
        if (tid < 64) sl4[tid + 2 * TPB] = a2;
        if (tid < 72) reinterpret_cast<float4*>(cs)[tid] = ac;

        __syncthreads();

        const float* c = cs + (tid >> 3) * 9;
        c00 = c[0]; c01 = c[1]; c02 = c[2];
        c10 = c[3]; c11 = c[4]; c12 = c[5];
        c20 = c[6]; c21 = c[7]; c22 = c[8];

        const float* l = lgs + tid * 9;
        l0 = l[0]; l1 = l[1]; l2 = l[2];
        l3 = l[3]; l4 = l[4]; l5 = l[5];
        l6 = l[6]; l7 = l[7]; l8 = l[8];
    } else {
        // tail block: direct (uncoalesced) path, correctness only
        int t = base + tid;
        if (t >= total) return;
        int n = t >> 3;
        const float* c = C + (size_t)n * 9;
        c00 = c[0]; c01 = c[1]; c02 = c[2];
        c10 = c[3]; c11 = c[4]; c12 = c[5];
        c20 = c[6]; c21 = c[7]; c22 = c[8];
        const float* l = Lg + (size_t)t * 9;
        l0 = l[0]; l1 = l[1]; l2 = l[2];
        l3 = l[3]; l4 = l[4]; l5 = l[5];
        l6 = l[6]; l7 = l[7]; l8 = l[8];
    }

    // Cofactor matrix of C (inv(C)^T = Cof / det)
    float f00 =  (c11 * c22 - c12 * c21);
    float f01 = -(c10 * c22 - c12 * c20);
    float f02 =  (c10 * c21 - c11 * c20);
    float f10 = -(c01 * c22 - c02 * c21);
    float f11 =  (c00 * c22 - c02 * c20);
    float f12 = -(c00 * c21 - c01 * c20);
    float f20 =  (c01 * c12 - c02 * c11);
    float f21 = -(c00 * c12 - c02 * c10);
    float f22 =  (c00 * c11 - c01 * c10);

    float det  = c00 * f00 + c01 * f01 + c02 * f02;
    float rdet = 1.0f / det;

    // M = C @ inv(C)^T = C @ (Cof * rdet)
    float m00 = (c00 * f00 + c01 * f10 + c02 * f20) * rdet;
    float m01 = (c00 * f01 + c01 * f11 + c02 * f21) * rdet;
    float m02 = (c00 * f02 + c01 * f12 + c02 * f22) * rdet;
    float m10 = (c10 * f00 + c11 * f10 + c12 * f20) * rdet;
    float m11 = (c10 * f01 + c11 * f11 + c12 * f21) * rdet;
    float m12 = (c10 * f02 + c11 * f12 + c12 * f22) * rdet;
    float m20 = (c20 * f00 + c21 * f10 + c22 * f20) * rdet;
    float m21 = (c20 * f01 + c21 * f11 + c22 * f21) * rdet;
    float m22 = (c20 * f02 + c21 * f12 + c22 * f22) * rdet;

    // dC = det(M)  (analytically 1, computed faithfully)
    float dC = m00 * (m11 * m22 - m12 * m21)
             - m01 * (m10 * m22 - m12 * m20)
             + m02 * (m10 * m21 - m11 * m20);

    // I = sum_ij C[i][j] * L[j][i]
    float I = c00 * l0 + c01 * l3 + c02 * l6
            + c10 * l1 + c11 * l4 + c12 * l7
            + c20 * l2 + c21 * l5 + c22 * l8;

    float trL = l0 + l4 + l8;
    float J = dC * trL;

    float2 r;
    r.x = I;
    r.y = J;
    reinterpret_cast<float2*>(out)[base + tid] = r;
}

extern "C" void kernel_launch(void* const* d_in, const int* in_sizes, int n_in,
                              void* d_out, int out_size, void* d_ws, size_t ws_size,
                              hipStream_t stream) {
    const float* Lg = (const float*)d_in[0];   // [N, 8, 3, 3] f32
    const float* C  = (const float*)d_in[1];   // [N, 3, 3] f32
    float* out = (float*)d_out;                // [N, 8, 2] f32

    int N = in_sizes[1] / 9;
    int total = N * 8;
    int blocks = (total + TPB - 1) / TPB;
    gik_kernel<<<blocks, TPB, 0, stream>>>(Lg, C, out, total);
}